// Round 12
// baseline (714.674 us; speedup 1.0000x reference)
//
#include <hip/hip_runtime.h>

#define N_NODES 100000
#define N_EDGES 600000
#define H 128
#define G_NUM 64
#define LN_EPS 1e-5f

// LDS bf16 row stride (conflict-free b128 frag reads)
#define WSTR 136

#define NTILES ((N_NODES + 63) / 64)     // 1563
#define BKT_CAP 1024                      // mean 384/tile, +32 sigma headroom

#define BKT_NB ((N_EDGES + 255) / 256)                       // 2344
#define WT_NB ((3 * 16384 + 255) / 256)                      // 192
#define CONV_NB ((N_NODES * 64 + 255) / 256)                 // 25000

typedef __attribute__((ext_vector_type(8))) short short8;
typedef __attribute__((ext_vector_type(4))) float floatx4;

__device__ __forceinline__ unsigned short f2bf(float x) {   // RNE fp32->bf16
    unsigned int u = __float_as_uint(x);
    u += 0x7fffu + ((u >> 16) & 1u);
    return (unsigned short)(u >> 16);
}

// ---------------------------------------------------------------------------
// Prep: tile-bucket edge scatter + frag-packed bf16 W^T + bf16 node mirror.
// One dispatch, disjoint block ranges (replaces hist+scan1+scan23+fill_wt).
// Bucket entry: (src<<6)|dstLocal. Overflow (statistically never) -> ovf list.
// ---------------------------------------------------------------------------
__global__ __launch_bounds__(256) void prep_kernel(
    const int* __restrict__ ei, int* __restrict__ cnt,
    unsigned int* __restrict__ bucket, int* __restrict__ ovf_cnt,
    unsigned int* __restrict__ ovf_pack, int* __restrict__ ovf_tile,
    const float* __restrict__ W1, const float* __restrict__ W2,
    const float* __restrict__ W3, unsigned short* __restrict__ WT,
    const float* __restrict__ node, unsigned int* __restrict__ nodeb)
{
    int gb = blockIdx.x;
    if (gb < BKT_NB) {
        int e = gb * 256 + threadIdx.x;
        if (e >= N_EDGES) return;
        int src = ei[e], dst = ei[N_EDGES + e];
        unsigned pack = ((unsigned)src << 6) | (unsigned)(dst & 63);
        int t = dst >> 6;
        int pos = atomicAdd(&cnt[t], 1);
        if (pos < BKT_CAP) {
            bucket[(size_t)t * BKT_CAP + pos] = pack;
        } else {                                  // safety valve, ~never taken
            int op = atomicAdd(ovf_cnt, 1);
            ovf_pack[op] = pack;
            ovf_tile[op] = t;
        }
    } else if (gb < BKT_NB + WT_NB) {
        // frag-linear W^T (r11 layout): f=(nt*4+kt)*64+lane, 8 bf16 contiguous
        int idx = (gb - BKT_NB) * 256 + threadIdx.x;
        if (idx >= 3 * 16384) return;
        int l = idx >> 14, r = idx & 16383;
        int frag = r >> 3, j = r & 7;
        int lane = frag & 63, ktnt = frag >> 6;
        int kt = ktnt & 3, nt = ktnt >> 2;
        int c = lane & 15, q = lane >> 4;
        int n = nt * 16 + c;
        int k = kt * 32 + q * 8 + j;
        const float* W = (l == 0) ? W1 : ((l == 1) ? W2 : W3);
        WT[l * 16384 + r] = f2bf(W[k * 128 + n]);
    } else {
        int i = (gb - BKT_NB - WT_NB) * 256 + threadIdx.x;
        if (i >= N_NODES * 64) return;
        float2 v = ((const float2*)node)[i];
        nodeb[i] = (unsigned)f2bf(v.x) | ((unsigned)f2bf(v.y) << 16);
    }
}

// ---------------------------------------------------------------------------
// MFMA helpers — B-fragments from frag-packed global WT (16B/lane coalesced)
// ---------------------------------------------------------------------------
__device__ __forceinline__ void gemm_frags(const unsigned short* __restrict__ hIn,
                                           const unsigned short* __restrict__ WTl,
                                           floatx4 acc[8], int w, int lane)
{
    const int c = lane & 15, q = lane >> 4;
#pragma unroll
    for (int nt = 0; nt < 8; ++nt) acc[nt] = (floatx4){0.f, 0.f, 0.f, 0.f};
#pragma unroll
    for (int kt = 0; kt < 4; ++kt) {
        short8 a = *(const short8*)&hIn[(w * 16 + c) * WSTR + kt * 32 + q * 8];
#pragma unroll
        for (int nt = 0; nt < 8; ++nt) {
            short8 b = *(const short8*)&WTl[(nt * 256 + kt * 64 + lane) * 8];
            acc[nt] = __builtin_amdgcn_mfma_f32_16x16x32_bf16(a, b, acc[nt], 0, 0, 0);
        }
    }
}

__device__ __forceinline__ void gemm_layer_ln(const unsigned short* __restrict__ hIn,
                                              unsigned short* __restrict__ hOut,
                                              const unsigned short* __restrict__ WTl,
                                              const float* __restrict__ bias,
                                              const float* __restrict__ g,
                                              const float* __restrict__ be,
                                              int w, int lane)
{
    const int c = lane & 15, q = lane >> 4;
    floatx4 acc[8];
    gemm_frags(hIn, WTl, acc, w, lane);

    float sum[4] = {0.f, 0.f, 0.f, 0.f};
    float sq[4]  = {0.f, 0.f, 0.f, 0.f};
#pragma unroll
    for (int nt = 0; nt < 8; ++nt) {
        float bv = bias[nt * 16 + c];
#pragma unroll
        for (int i = 0; i < 4; ++i) {
            float vv = acc[nt][i] + bv;
            acc[nt][i] = vv;
            sum[i] += vv; sq[i] += vv * vv;
        }
    }
#pragma unroll
    for (int m = 1; m < 16; m <<= 1) {
#pragma unroll
        for (int i = 0; i < 4; ++i) {
            sum[i] += __shfl_xor(sum[i], m);
            sq[i]  += __shfl_xor(sq[i], m);
        }
    }
    float mu[4], rstd[4];
#pragma unroll
    for (int i = 0; i < 4; ++i) {
        mu[i]   = sum[i] * (1.0f / 128.0f);
        rstd[i] = rsqrtf(sq[i] * (1.0f / 128.0f) - mu[i] * mu[i] + LN_EPS);
    }
#pragma unroll
    for (int nt = 0; nt < 8; ++nt) {
        float gw = g[nt * 16 + c];
        float bw = be[nt * 16 + c];
#pragma unroll
        for (int i = 0; i < 4; ++i) {
            float val = fmaxf(0.f, (acc[nt][i] - mu[i]) * rstd[i] * gw + bw);
            hOut[(w * 16 + q * 4 + i) * WSTR + nt * 16 + c] = f2bf(val);
        }
    }
}

// ---------------------------------------------------------------------------
// Fused kernel (one tile/block): bucket gather -> LDS fp32 acc (split planes,
// conflict-free ds_add_f32) -> bf16 hA (union with acc; barrier-separated)
// -> 3x MFMA GEMM (LN fused) -> fp32 out + per-graph stats.
// ---------------------------------------------------------------------------
__global__ __launch_bounds__(256, 4) void fused_kernel(
    const float* __restrict__ node, const unsigned int* __restrict__ nodeb,
    const int* __restrict__ cnt, const unsigned int* __restrict__ bucket,
    const int* __restrict__ ovf_cnt, const unsigned int* __restrict__ ovf_pack,
    const int* __restrict__ ovf_tile, const float* __restrict__ epsp,
    const unsigned short* __restrict__ WT,
    const float* __restrict__ b1, const float* __restrict__ g1,
    const float* __restrict__ be1,
    const float* __restrict__ b2, const float* __restrict__ g2,
    const float* __restrict__ be2,
    const float* __restrict__ b3, const int* __restrict__ batch,
    float* __restrict__ out, float* __restrict__ gstat)
{
    // U: 34.8 KB union. Gather phase: accE[64*64] | accO[64*64] fp32 planes
    // (lane-stride-1 -> conflict-free). MLP phase: hA | hB bf16 (64*WSTR each).
    __shared__ float U[8704];
    __shared__ float prm[7 * 128];
    __shared__ float s_gsum[G_NUM], s_gsq[G_NUM], s_gcnt[G_NUM];
    // ~40 KB -> 4 blocks/CU

    const int tid = threadIdx.x;
    const int w = tid >> 6, lane = tid & 63;
    const int t = blockIdx.x;
    const int row0 = t * 64;

#pragma unroll
    for (int i = 0; i < 34; ++i) U[tid + i * 256] = 0.f;    // 8704 = 34*256
    if (tid < G_NUM) { s_gsum[tid] = 0.f; s_gsq[tid] = 0.f; s_gcnt[tid] = 0.f; }
    {
        const float* srcs[7] = {b1, g1, be1, b2, g2, be2, b3};
#pragma unroll
        for (int k = 0; k < 4; ++k) {
            int i = tid + k * 256;
            if (i < 7 * 128) prm[i] = srcs[i >> 7][i & 127];
        }
    }
    __syncthreads();

    float* accE = U;                 // col 2*lane
    float* accO = U + 4096;          // col 2*lane+1
    const float2* np2 = (const float2*)node;

    // ---- bucket gather: whole tile shared by all 4 waves (no row imbalance)
    {
        int m = cnt[t]; if (m > BKT_CAP) m = BKT_CAP;
        const unsigned* bkt = bucket + (size_t)t * BKT_CAP;
        for (int b0 = w * 64; b0 < m; b0 += 256) {
            int mm = m - b0; if (mm > 64) mm = 64;
            unsigned pk = (lane < mm) ? bkt[b0 + lane] : 0u;  // coalesced chunk
            int j = 0;
            if (nodeb) {
                for (; j + 4 <= mm; j += 4) {
                    unsigned p0 = __shfl(pk, j),     p1 = __shfl(pk, j + 1);
                    unsigned p2 = __shfl(pk, j + 2), p3 = __shfl(pk, j + 3);
                    unsigned v0 = nodeb[(size_t)(p0 >> 6) * 64 + lane];
                    unsigned v1 = nodeb[(size_t)(p1 >> 6) * 64 + lane];
                    unsigned v2 = nodeb[(size_t)(p2 >> 6) * 64 + lane];
                    unsigned v3 = nodeb[(size_t)(p3 >> 6) * 64 + lane];
                    atomicAdd(&accE[(p0 & 63) * 64 + lane], __uint_as_float(v0 << 16));
                    atomicAdd(&accO[(p0 & 63) * 64 + lane], __uint_as_float(v0 & 0xffff0000u));
                    atomicAdd(&accE[(p1 & 63) * 64 + lane], __uint_as_float(v1 << 16));
                    atomicAdd(&accO[(p1 & 63) * 64 + lane], __uint_as_float(v1 & 0xffff0000u));
                    atomicAdd(&accE[(p2 & 63) * 64 + lane], __uint_as_float(v2 << 16));
                    atomicAdd(&accO[(p2 & 63) * 64 + lane], __uint_as_float(v2 & 0xffff0000u));
                    atomicAdd(&accE[(p3 & 63) * 64 + lane], __uint_as_float(v3 << 16));
                    atomicAdd(&accO[(p3 & 63) * 64 + lane], __uint_as_float(v3 & 0xffff0000u));
                }
                for (; j < mm; ++j) {
                    unsigned p0 = __shfl(pk, j);
                    unsigned v0 = nodeb[(size_t)(p0 >> 6) * 64 + lane];
                    atomicAdd(&accE[(p0 & 63) * 64 + lane], __uint_as_float(v0 << 16));
                    atomicAdd(&accO[(p0 & 63) * 64 + lane], __uint_as_float(v0 & 0xffff0000u));
                }
            } else {
                for (; j < mm; ++j) {
                    unsigned p0 = __shfl(pk, j);
                    float2 v = np2[(size_t)(p0 >> 6) * 64 + lane];
                    atomicAdd(&accE[(p0 & 63) * 64 + lane], v.x);
                    atomicAdd(&accO[(p0 & 63) * 64 + lane], v.y);
                }
            }
        }
        // overflow list (expected 0 entries; correctness valve)
        int oc = *ovf_cnt;
        for (int b0 = w * 64; b0 < oc; b0 += 256) {
            int mm = oc - b0; if (mm > 64) mm = 64;
            int tt = -1; unsigned pk = 0u;
            if (lane < mm) { tt = ovf_tile[b0 + lane]; pk = ovf_pack[b0 + lane]; }
            for (int j = 0; j < mm; ++j) {
                if (__shfl(tt, j) != t) continue;
                unsigned p0 = __shfl(pk, j);
                float vx, vy;
                if (nodeb) {
                    unsigned v = nodeb[(size_t)(p0 >> 6) * 64 + lane];
                    vx = __uint_as_float(v << 16);
                    vy = __uint_as_float(v & 0xffff0000u);
                } else {
                    float2 v = np2[(size_t)(p0 >> 6) * 64 + lane];
                    vx = v.x; vy = v.y;
                }
                atomicAdd(&accE[(p0 & 63) * 64 + lane], vx);
                atomicAdd(&accO[(p0 & 63) * 64 + lane], vy);
            }
        }
    }
    __syncthreads();                     // all ds_adds done

    // ---- read acc + (1+eps)*own into regs, then repack U as bf16 hA
    const float epsv = 1.0f + epsp[0];
    float rx[16], ry[16];
#pragma unroll
    for (int i = 0; i < 16; ++i) {
        int r = w * 16 + i;
        int n = row0 + r;
        float ax = accE[r * 64 + lane], ay = accO[r * 64 + lane];
        if (n < N_NODES) {
            float2 o = np2[(size_t)n * 64 + lane];
            ax += epsv * o.x; ay += epsv * o.y;
        } else { ax = 0.f; ay = 0.f; }
        rx[i] = ax; ry[i] = ay;
    }
    __syncthreads();                     // all acc reads done before overwrite

    unsigned short* hA = (unsigned short*)U;
    unsigned short* hB = (unsigned short*)U + 64 * WSTR;
#pragma unroll
    for (int i = 0; i < 16; ++i) {
        unsigned pack = (unsigned)f2bf(rx[i]) | ((unsigned)f2bf(ry[i]) << 16);
        ((unsigned int*)&hA[(w * 16 + i) * WSTR])[lane] = pack;
    }
    // hA/hB rows are wave-private from here on — no more barriers needed.

    gemm_layer_ln(hA, hB, WT,         &prm[0],   &prm[128], &prm[256], w, lane);
    gemm_layer_ln(hB, hA, WT + 16384, &prm[384], &prm[512], &prm[640], w, lane);

    // layer 3 -> global + stats
    {
        const int c = lane & 15, q = lane >> 4;
        floatx4 acc3[8];
        gemm_frags(hA, WT + 32768, acc3, w, lane);
        float sum[4] = {0.f, 0.f, 0.f, 0.f};
        float sq[4]  = {0.f, 0.f, 0.f, 0.f};
#pragma unroll
        for (int nt = 0; nt < 8; ++nt) {
            float bv = prm[768 + nt * 16 + c];
#pragma unroll
            for (int i = 0; i < 4; ++i) {
                float vv = acc3[nt][i] + bv;
                size_t nrow = (size_t)row0 + w * 16 + q * 4 + i;
                if (nrow < N_NODES)
                    out[nrow * H + nt * 16 + c] = vv;
                sum[i] += vv; sq[i] += vv * vv;
            }
        }
#pragma unroll
        for (int m = 1; m < 16; m <<= 1) {
#pragma unroll
            for (int i = 0; i < 4; ++i) {
                sum[i] += __shfl_xor(sum[i], m);
                sq[i]  += __shfl_xor(sq[i], m);
            }
        }
        if (c == 0) {
#pragma unroll
            for (int i = 0; i < 4; ++i) {
                size_t nrow = (size_t)row0 + w * 16 + q * 4 + i;
                if (nrow < N_NODES) {
                    int g = batch[nrow];
                    atomicAdd(&s_gsum[g], sum[i]);
                    atomicAdd(&s_gsq[g], sq[i]);
                    atomicAdd(&s_gcnt[g], 1.0f);
                }
            }
        }
    }
    __syncthreads();
    if (tid < G_NUM && s_gcnt[tid] > 0.f) {
        unsafeAtomicAdd(&gstat[tid], s_gsum[tid]);
        unsafeAtomicAdd(&gstat[G_NUM + tid], s_gsq[tid]);
        unsafeAtomicAdd(&gstat[2 * G_NUM + tid], s_gcnt[tid]);
    }
}

// ---------------------------------------------------------------------------
// Graph-LN apply + ReLU (finalize folded in)
// ---------------------------------------------------------------------------
__global__ __launch_bounds__(256) void final_ln_kernel(
    float* __restrict__ h3, const int* __restrict__ batch,
    const float* __restrict__ lnw, const float* __restrict__ lnb,
    const float* __restrict__ gstat)
{
    int idx4 = blockIdx.x * 256 + threadIdx.x;
    if (idx4 >= N_NODES * 32) return;
    int node = idx4 >> 5;
    int c4 = (idx4 & 31) * 4;
    int g = batch[node];
    float s   = gstat[g];
    float qq  = gstat[G_NUM + g];
    float cnt = gstat[2 * G_NUM + g];
    float norm = fmaxf(cnt * (float)H, 1.0f);
    float mean = s / norm;
    float var  = qq / norm - mean * mean;
    float inv  = rsqrtf(var + LN_EPS);
    float4 v = ((const float4*)h3)[idx4];
    float4 w = *(const float4*)&lnw[c4];
    float4 b = *(const float4*)&lnb[c4];
    v.x = fmaxf(0.f, (v.x - mean) * inv * w.x + b.x);
    v.y = fmaxf(0.f, (v.y - mean) * inv * w.y + b.y);
    v.z = fmaxf(0.f, (v.z - mean) * inv * w.z + b.z);
    v.w = fmaxf(0.f, (v.w - mean) * inv * w.w + b.w);
    ((float4*)h3)[idx4] = v;
}

// ---------------------------------------------------------------------------
extern "C" void kernel_launch(void* const* d_in, const int* in_sizes, int n_in,
                              void* d_out, int out_size, void* d_ws, size_t ws_size,
                              hipStream_t stream)
{
    const float* node  = (const float*)d_in[0];
    const int*   ei    = (const int*)d_in[1];
    // d_in[2] = edge_attr (unused)
    const int*   batch = (const int*)d_in[3];
    const float* epsp  = (const float*)d_in[4];
    const float* W1    = (const float*)d_in[5];
    const float* b1    = (const float*)d_in[6];
    const float* g1    = (const float*)d_in[7];
    const float* be1   = (const float*)d_in[8];
    const float* W2    = (const float*)d_in[9];
    const float* b2    = (const float*)d_in[10];
    const float* g2    = (const float*)d_in[11];
    const float* be2   = (const float*)d_in[12];
    const float* W3    = (const float*)d_in[13];
    const float* b3    = (const float*)d_in[14];
    const float* lnw   = (const float*)d_in[15];
    const float* lnb   = (const float*)d_in[16];

    float* out = (float*)d_out;

    // ws layout (int units):
    //   gstat 0..320 | ovf_cnt @320 | cnt @512..2075 | bucket @2080 (1563*1024)
    //   ovf_pack @1602592 (E) | ovf_tile @2202592 (E) | WT @2802592 (24576)
    //   nodeb @2827168 (N*64)  -> total ~36.9 MB
    int* base = (int*)d_ws;
    float* gstat   = (float*)d_ws;
    int*   ovf_cnt = base + 320;
    int*   cnt     = base + 512;
    unsigned int* bucket   = (unsigned int*)(base + 2080);
    unsigned int* ovf_pack = (unsigned int*)(base + 1602592);
    int*          ovf_tile = base + 2202592;
    unsigned short* WT     = (unsigned short*)(base + 2802592);  // 16B aligned
    unsigned int* nodeb = nullptr;
    {
        size_t need = (2827168ull + (size_t)N_NODES * 64) * 4;   // ~36.9 MB
        if (ws_size >= need) nodeb = (unsigned int*)(base + 2827168);
    }

    // zero gstat + ovf_cnt + cnt in one small memset (8.3 KB)
    hipMemsetAsync(d_ws, 0, 2080 * sizeof(int), stream);

    int prep_grid = BKT_NB + WT_NB + (nodeb ? CONV_NB : 0);
    prep_kernel<<<prep_grid, 256, 0, stream>>>(
        ei, cnt, bucket, ovf_cnt, ovf_pack, ovf_tile,
        W1, W2, W3, WT, node, nodeb);

    fused_kernel<<<NTILES, 256, 0, stream>>>(
        node, nodeb, cnt, bucket, ovf_cnt, ovf_pack, ovf_tile, epsp, WT,
        b1, g1, be1, b2, g2, be2, b3, batch, out, gstat);

    final_ln_kernel<<<(N_NODES * 32 + 255) / 256, 256, 0, stream>>>(
        out, batch, lnw, lnb, gstat);
}

// Round 13
// 295.214 us; speedup vs baseline: 2.4209x; 2.4209x over previous
//
#include <hip/hip_runtime.h>

#define N_NODES 100000
#define N_EDGES 600000
#define H 128
#define G_NUM 64
#define LN_EPS 1e-5f

// LDS bf16 row stride (conflict-free b128 frag reads)
#define WSTR 136

#define NTILES ((N_NODES + 63) / 64)     // 1563

#define SCAN_CHUNK 1024
#define SCAN_NB ((N_NODES + SCAN_CHUNK - 1) / SCAN_CHUNK)   // 98
#define FILL_NB ((N_EDGES + 255) / 256)                      // 2344
#define WT_NB ((3 * 16384 + 255) / 256)                      // 192

#define SCRATCH_PW 1088   // ints per wave of csr scratch (hB reuse: 4352 ints/4)

typedef __attribute__((ext_vector_type(8))) short short8;
typedef __attribute__((ext_vector_type(4))) float floatx4;

__device__ __forceinline__ unsigned short f2bf(float x) {   // RNE fp32->bf16
    unsigned int u = __float_as_uint(x);
    u += 0x7fffu + ((u >> 16) & 1u);
    return (unsigned short)(u >> 16);
}

// ---------------------------------------------------------------------------
// CSR build (r11-proven)
// ---------------------------------------------------------------------------
__global__ __launch_bounds__(256) void hist_kernel(
    const int* __restrict__ ei, int* __restrict__ deg)
{
    int e = blockIdx.x * 256 + threadIdx.x;
    if (e >= N_EDGES) return;
    atomicAdd(&deg[ei[N_EDGES + e]], 1);
}

__global__ __launch_bounds__(256) void scan1_kernel(
    const int* __restrict__ deg, int* __restrict__ off,
    int* __restrict__ blksum)
{
    __shared__ int sA[256], sB[256];
    const int tid = threadIdx.x;
    const int base = blockIdx.x * SCAN_CHUNK + tid * 4;
    int v[4];
#pragma unroll
    for (int j = 0; j < 4; ++j) {
        int i = base + j;
        v[j] = (i < N_NODES) ? deg[i] : 0;
    }
    int tsum = v[0] + v[1] + v[2] + v[3];
    int* a = sA; int* b = sB;
    a[tid] = tsum;
    __syncthreads();
#pragma unroll
    for (int o = 1; o < 256; o <<= 1) {
        int t = a[tid] + ((tid >= o) ? a[tid - o] : 0);
        b[tid] = t;
        __syncthreads();
        int* tmp = a; a = b; b = tmp;
    }
    int run = a[tid] - tsum;
#pragma unroll
    for (int j = 0; j < 4; ++j) {
        int i = base + j;
        if (i < N_NODES) off[i] = run;
        run += v[j];
    }
    if (tid == 255) blksum[blockIdx.x] = a[255];
}

__global__ __launch_bounds__(256) void scan23_kernel(
    int* __restrict__ off, const int* __restrict__ blksum,
    int* __restrict__ cursor)
{
    __shared__ int sA[128], sB[128];
    const int tid = threadIdx.x;
    if (tid < 128) sA[tid] = (tid < SCAN_NB) ? blksum[tid] : 0;
    __syncthreads();
    int* a = sA; int* b = sB;
#pragma unroll
    for (int o = 1; o < 128; o <<= 1) {
        int t = 0;
        if (tid < 128) t = a[tid] + ((tid >= o) ? a[tid - o] : 0);
        __syncthreads();
        if (tid < 128) b[tid] = t;
        __syncthreads();
        int* tmp = a; a = b; b = tmp;
    }
    int excl = 0;
    if (tid < 128) excl = a[tid] - ((tid < SCAN_NB) ? blksum[tid] : 0);
    __syncthreads();
    if (tid < 128) sA[tid] = excl;
    __syncthreads();

    int i = blockIdx.x * 256 + tid;
    if (i < N_NODES) {
        int val = off[i] + sA[i >> 10];
        off[i] = val;
        cursor[i] = val;
    }
    if (i == 0) off[N_NODES] = N_EDGES;
}

// fill + FRAGMENT-PACKED bf16 weights (r11 layout), one dispatch.
// WT frag-linear: f=(nt*4+kt)*64+lane (lane=c+16q): 8 contiguous bf16 =
// W^T[n=nt*16+c][k=kt*32+q*8 .. +8] -> consumer loads 16B/lane coalesced.
__global__ __launch_bounds__(256) void fill_wt_kernel(
    const int* __restrict__ ei, int* __restrict__ cursor,
    int* __restrict__ csr,
    const float* __restrict__ W1, const float* __restrict__ W2,
    const float* __restrict__ W3, unsigned short* __restrict__ WT)
{
    int gb = blockIdx.x;
    if (gb < FILL_NB) {
        int e = gb * 256 + threadIdx.x;
        if (e >= N_EDGES) return;
        int dst = ei[N_EDGES + e];
        int pos = atomicAdd(&cursor[dst], 1);
        csr[pos] = ei[e];
    } else {
        int idx = (gb - FILL_NB) * 256 + threadIdx.x;
        if (idx >= 3 * 16384) return;
        int l = idx >> 14, r = idx & 16383;
        int frag = r >> 3, j = r & 7;
        int lane = frag & 63, ktnt = frag >> 6;
        int kt = ktnt & 3, nt = ktnt >> 2;
        int c = lane & 15, q = lane >> 4;
        int n = nt * 16 + c;
        int k = kt * 32 + q * 8 + j;
        const float* W = (l == 0) ? W1 : ((l == 1) ? W2 : W3);
        WT[l * 16384 + r] = f2bf(W[k * 128 + n]);
    }
}

// ---------------------------------------------------------------------------
// MFMA helpers — B-fragments from frag-packed global WT (16B/lane coalesced)
// ---------------------------------------------------------------------------
__device__ __forceinline__ void gemm_frags(const unsigned short* __restrict__ hIn,
                                           const unsigned short* __restrict__ WTl,
                                           floatx4 acc[8], int w, int lane)
{
    const int c = lane & 15, q = lane >> 4;
#pragma unroll
    for (int nt = 0; nt < 8; ++nt) acc[nt] = (floatx4){0.f, 0.f, 0.f, 0.f};
#pragma unroll
    for (int kt = 0; kt < 4; ++kt) {
        short8 a = *(const short8*)&hIn[(w * 16 + c) * WSTR + kt * 32 + q * 8];
#pragma unroll
        for (int nt = 0; nt < 8; ++nt) {
            short8 b = *(const short8*)&WTl[(nt * 256 + kt * 64 + lane) * 8];
            acc[nt] = __builtin_amdgcn_mfma_f32_16x16x32_bf16(a, b, acc[nt], 0, 0, 0);
        }
    }
}

// GEMM + bias + per-row LayerNorm + ReLU fused in registers -> bf16 to LDS.
__device__ __forceinline__ void gemm_layer_ln(const unsigned short* __restrict__ hIn,
                                              unsigned short* __restrict__ hOut,
                                              const unsigned short* __restrict__ WTl,
                                              const float* __restrict__ bias,
                                              const float* __restrict__ g,
                                              const float* __restrict__ be,
                                              int w, int lane)
{
    const int c = lane & 15, q = lane >> 4;
    floatx4 acc[8];
    gemm_frags(hIn, WTl, acc, w, lane);

    float sum[4] = {0.f, 0.f, 0.f, 0.f};
    float sq[4]  = {0.f, 0.f, 0.f, 0.f};
#pragma unroll
    for (int nt = 0; nt < 8; ++nt) {
        float bv = bias[nt * 16 + c];
#pragma unroll
        for (int i = 0; i < 4; ++i) {
            float vv = acc[nt][i] + bv;
            acc[nt][i] = vv;
            sum[i] += vv; sq[i] += vv * vv;
        }
    }
#pragma unroll
    for (int m = 1; m < 16; m <<= 1) {
#pragma unroll
        for (int i = 0; i < 4; ++i) {
            sum[i] += __shfl_xor(sum[i], m);
            sq[i]  += __shfl_xor(sq[i], m);
        }
    }
    float mu[4], rstd[4];
#pragma unroll
    for (int i = 0; i < 4; ++i) {
        mu[i]   = sum[i] * (1.0f / 128.0f);
        rstd[i] = rsqrtf(sq[i] * (1.0f / 128.0f) - mu[i] * mu[i] + LN_EPS);
    }
#pragma unroll
    for (int nt = 0; nt < 8; ++nt) {
        float gw = g[nt * 16 + c];
        float bw = be[nt * 16 + c];
#pragma unroll
        for (int i = 0; i < 4; ++i) {
            float val = fmaxf(0.f, (acc[nt][i] - mu[i]) * rstd[i] * gw + bw);
            hOut[(w * 16 + q * 4 + i) * WSTR + nt * 16 + c] = f2bf(val);
        }
    }
}

// ---------------------------------------------------------------------------
// Fused kernel (r6 gather structure + r11 packed-WT GEMM):
// pipelined fp32 gather (LDS-scratch csr, 4 chains) -> bf16 hA ->
// 3x MFMA GEMM (LN fused) -> fp32 out + per-graph stats.
// ---------------------------------------------------------------------------
__global__ __launch_bounds__(256, 4) void fused_mlp_kernel(
    const float* __restrict__ node, const int* __restrict__ off,
    const int* __restrict__ csr, const float* __restrict__ epsp,
    const unsigned short* __restrict__ WT,
    const float* __restrict__ b1, const float* __restrict__ g1,
    const float* __restrict__ be1,
    const float* __restrict__ b2, const float* __restrict__ g2,
    const float* __restrict__ be2,
    const float* __restrict__ b3, const int* __restrict__ batch,
    float* __restrict__ out, float* __restrict__ gstat)
{
    __shared__ unsigned short hA[64 * WSTR];    // 17.4 KB
    __shared__ unsigned short hB[64 * WSTR];    // 17.4 KB (gather csr scratch too)
    __shared__ float prm[7 * 128];              // 3.6 KB
    __shared__ float s_gsum[G_NUM], s_gsq[G_NUM], s_gcnt[G_NUM];
    // total ~39.2 KB -> 4 blocks/CU

    const int tid = threadIdx.x;
    const int w = tid >> 6, lane = tid & 63;
    const int row0 = blockIdx.x * 64;

    if (tid < G_NUM) { s_gsum[tid] = 0.f; s_gsq[tid] = 0.f; s_gcnt[tid] = 0.f; }
    {
        const float* srcs[7] = {b1, g1, be1, b2, g2, be2, b3};
#pragma unroll
        for (int t = 0; t < 4; ++t) {
            int i = tid + t * 256;
            if (i < 7 * 128) prm[i] = srcs[i >> 7][i & 127];
        }
    }

    // ---- pipelined gather: h0 = (1+eps)*x + sum neighbors (fp32) -> hA bf16
    {
        const float2* np2 = (const float2*)node;
        const float epsv = 1.0f + epsp[0];
        const int n0 = row0 + w * 16;
        int oidx = n0 + ((lane < 17) ? lane : 16);
        if (oidx > N_NODES) oidx = N_NODES;
        const int offl = off[oidx];
        const int e_begin = __shfl(offl, 0);
        const int e_end   = __shfl(offl, 16);
        const int cnt = e_end - e_begin;

        float2 acc[16];
#pragma unroll
        for (int i = 0; i < 16; ++i) {
            int n = n0 + i;
            if (n < N_NODES) {
                float2 own = np2[(size_t)n * 64 + lane];
                acc[i].x = epsv * own.x; acc[i].y = epsv * own.y;
            } else {
                acc[i].x = 0.f; acc[i].y = 0.f;
            }
        }

        if (cnt <= SCRATCH_PW) {
            int* scr = ((int*)hB) + w * SCRATCH_PW;
            for (int k = lane; k < cnt; k += 64) scr[k] = csr[e_begin + k];
            __threadfence_block();       // drain ds_writes before same-wave reads

#pragma unroll
            for (int g4 = 0; g4 < 4; ++g4) {
                int p[4], e[4];
#pragma unroll
                for (int j = 0; j < 4; ++j) {
                    p[j] = __shfl(offl, g4 * 4 + j) - e_begin;
                    e[j] = __shfl(offl, g4 * 4 + j + 1) - e_begin;
                }
                float2 vc[4]; bool ac[4];
#pragma unroll
                for (int j = 0; j < 4; ++j) {
                    ac[j] = p[j] < e[j];
                    vc[j] = make_float2(0.f, 0.f);
                    if (ac[j]) vc[j] = np2[(size_t)scr[p[j]] * 64 + lane];
                }
                while (ac[0] || ac[1] || ac[2] || ac[3]) {
                    float2 vn[4]; bool an[4];
#pragma unroll
                    for (int j = 0; j < 4; ++j) {   // prefetch next round
                        an[j] = (p[j] + 1) < e[j];
                        vn[j] = make_float2(0.f, 0.f);
                        if (an[j]) vn[j] = np2[(size_t)scr[p[j] + 1] * 64 + lane];
                    }
#pragma unroll
                    for (int j = 0; j < 4; ++j) {   // consume current
                        if (ac[j]) {
                            acc[g4 * 4 + j].x += vc[j].x;
                            acc[g4 * 4 + j].y += vc[j].y;
                            p[j] += 1;
                        }
                        ac[j] = an[j];
                        vc[j] = vn[j];
                    }
                }
            }
        } else {
            // pathological-degree fallback (rare): serial fp32
            for (int i = 0; i < 16; ++i) {
                int n = n0 + i;
                if (n >= N_NODES) continue;
                for (int j = off[n]; j < off[n + 1]; ++j) {
                    float2 v = np2[(size_t)csr[j] * 64 + lane];
                    acc[i].x += v.x; acc[i].y += v.y;
                }
            }
        }
#pragma unroll
        for (int i = 0; i < 16; ++i) {
            unsigned int pack = (unsigned)f2bf(acc[i].x) |
                                ((unsigned)f2bf(acc[i].y) << 16);
            ((unsigned int*)&hA[(w * 16 + i) * WSTR])[lane] = pack;
        }
    }
    __syncthreads();   // prm visible; hB scratch reads drained before reuse

    gemm_layer_ln(hA, hB, WT,         &prm[0],   &prm[128], &prm[256], w, lane);
    gemm_layer_ln(hB, hA, WT + 16384, &prm[384], &prm[512], &prm[640], w, lane);

    // layer 3 -> global + stats
    {
        const int c = lane & 15, q = lane >> 4;
        floatx4 acc3[8];
        gemm_frags(hA, WT + 32768, acc3, w, lane);
        float sum[4] = {0.f, 0.f, 0.f, 0.f};
        float sq[4]  = {0.f, 0.f, 0.f, 0.f};
#pragma unroll
        for (int nt = 0; nt < 8; ++nt) {
            float bv = prm[768 + nt * 16 + c];
#pragma unroll
            for (int i = 0; i < 4; ++i) {
                float vv = acc3[nt][i] + bv;
                size_t nrow = (size_t)row0 + w * 16 + q * 4 + i;
                if (nrow < N_NODES)
                    out[nrow * H + nt * 16 + c] = vv;
                sum[i] += vv; sq[i] += vv * vv;
            }
        }
#pragma unroll
        for (int m = 1; m < 16; m <<= 1) {
#pragma unroll
            for (int i = 0; i < 4; ++i) {
                sum[i] += __shfl_xor(sum[i], m);
                sq[i]  += __shfl_xor(sq[i], m);
            }
        }
        if (c == 0) {
#pragma unroll
            for (int i = 0; i < 4; ++i) {
                size_t nrow = (size_t)row0 + w * 16 + q * 4 + i;
                if (nrow < N_NODES) {
                    int g = batch[nrow];
                    atomicAdd(&s_gsum[g], sum[i]);
                    atomicAdd(&s_gsq[g], sq[i]);
                    atomicAdd(&s_gcnt[g], 1.0f);
                }
            }
        }
    }
    __syncthreads();
    if (tid < G_NUM && s_gcnt[tid] > 0.f) {
        unsafeAtomicAdd(&gstat[tid], s_gsum[tid]);
        unsafeAtomicAdd(&gstat[G_NUM + tid], s_gsq[tid]);
        unsafeAtomicAdd(&gstat[2 * G_NUM + tid], s_gcnt[tid]);
    }
}

// ---------------------------------------------------------------------------
// Graph-LN apply + ReLU (finalize folded in)
// ---------------------------------------------------------------------------
__global__ __launch_bounds__(256) void final_ln_kernel(
    float* __restrict__ h3, const int* __restrict__ batch,
    const float* __restrict__ lnw, const float* __restrict__ lnb,
    const float* __restrict__ gstat)
{
    int idx4 = blockIdx.x * 256 + threadIdx.x;
    if (idx4 >= N_NODES * 32) return;
    int node = idx4 >> 5;
    int c4 = (idx4 & 31) * 4;
    int g = batch[node];
    float s   = gstat[g];
    float qq  = gstat[G_NUM + g];
    float cnt = gstat[2 * G_NUM + g];
    float norm = fmaxf(cnt * (float)H, 1.0f);
    float mean = s / norm;
    float var  = qq / norm - mean * mean;
    float inv  = rsqrtf(var + LN_EPS);
    float4 v = ((const float4*)h3)[idx4];
    float4 w = *(const float4*)&lnw[c4];
    float4 b = *(const float4*)&lnb[c4];
    v.x = fmaxf(0.f, (v.x - mean) * inv * w.x + b.x);
    v.y = fmaxf(0.f, (v.y - mean) * inv * w.y + b.y);
    v.z = fmaxf(0.f, (v.z - mean) * inv * w.z + b.z);
    v.w = fmaxf(0.f, (v.w - mean) * inv * w.w + b.w);
    ((float4*)h3)[idx4] = v;
}

// ---------------------------------------------------------------------------
extern "C" void kernel_launch(void* const* d_in, const int* in_sizes, int n_in,
                              void* d_out, int out_size, void* d_ws, size_t ws_size,
                              hipStream_t stream)
{
    const float* node  = (const float*)d_in[0];
    const int*   ei    = (const int*)d_in[1];
    // d_in[2] = edge_attr (unused)
    const int*   batch = (const int*)d_in[3];
    const float* epsp  = (const float*)d_in[4];
    const float* W1    = (const float*)d_in[5];
    const float* b1    = (const float*)d_in[6];
    const float* g1    = (const float*)d_in[7];
    const float* be1   = (const float*)d_in[8];
    const float* W2    = (const float*)d_in[9];
    const float* b2    = (const float*)d_in[10];
    const float* g2    = (const float*)d_in[11];
    const float* be2   = (const float*)d_in[12];
    const float* W3    = (const float*)d_in[13];
    const float* b3    = (const float*)d_in[14];
    const float* lnw   = (const float*)d_in[15];
    const float* lnb   = (const float*)d_in[16];

    float* out = (float*)d_out;

    // ws layout (ints): gstat 512 | deg N | off N+1 | cursor N | csr E |
    //                   blksum 98+pad | WT (3*16k bf16)   ~3.7 MB
    int* base = (int*)d_ws;
    float* gstat  = (float*)d_ws;
    int*   deg    = base + 512;
    int*   off    = deg + N_NODES;
    int*   cursor = off + N_NODES + 1;
    int*   csr    = cursor + N_NODES;
    int*   blksum = csr + N_EDGES;
    unsigned short* WT = (unsigned short*)(base + 900612);   // 16B-aligned

    // single memset covers gstat (512 floats) + adjacent deg (N ints)
    hipMemsetAsync(d_ws, 0, (512 + N_NODES) * sizeof(int), stream);

    hist_kernel<<<(N_EDGES + 255) / 256, 256, 0, stream>>>(ei, deg);
    scan1_kernel<<<SCAN_NB, 256, 0, stream>>>(deg, off, blksum);
    scan23_kernel<<<(N_NODES + 255) / 256, 256, 0, stream>>>(off, blksum, cursor);
    fill_wt_kernel<<<FILL_NB + WT_NB, 256, 0, stream>>>(ei, cursor, csr,
                                                        W1, W2, W3, WT);

    fused_mlp_kernel<<<NTILES, 256, 0, stream>>>(
        node, off, csr, epsp, WT, b1, g1, be1, b2, g2, be2, b3, batch,
        out, gstat);

    final_ln_kernel<<<(N_NODES * 32 + 255) / 256, 256, 0, stream>>>(
        out, batch, lnw, lnb, gstat);
}